// Round 5
// baseline (3615.235 us; speedup 1.0000x reference)
//
#include <hip/hip_runtime.h>

// ---------------------------------------------------------------------------
// SparsePoolingLayer: u0 = conv5x5_valid(x, W_ff); iterate
//   u <- 0.5*u + 0.5*(u0 - W_rec @ a); a = relu(u - thr)
// until ||u_new - u||/||u_new|| < 1e-3 (device-checked), max 41 iterations.
//
// R3 design (R4 = bugfix): fused per-n-tile iteration. Block = 64 n x ALL
// 256 oc, so `a` never touches HBM (computed into LDS from the staged
// u-tile). wrec pre-swizzled into per-lane MFMA fragment order, read
// directly from L2 (128 KB resident). u stored bf16 [n][oc]. u0 bf16
// [n][oc]. Logical HBM/iter: 177 MB (was ~708).
// R4 fix: staging load was uint2 (4 shorts) but consumed as 8 shorts ->
// upper half of every a-row was stack garbage -> recurrence diverged to
// 1e37. Now int4 (16 B = 8 shorts).
// ---------------------------------------------------------------------------

typedef __attribute__((ext_vector_type(8))) short short8;
typedef __attribute__((ext_vector_type(4))) float f32x4;

#define NTOT 115200   // 32*60*60
#define CHW  262144   // 64*64*64
#define HW2  4096     // 64*64
#define LDA  264      // a_lds row stride in shorts (528 B -> conflict-free)

__device__ __forceinline__ unsigned short f2bf(float f) {
  unsigned int u = __float_as_uint(f);
  unsigned int r = u + 0x7FFFu + ((u >> 16) & 1u);
  return (unsigned short)(r >> 16);
}
__device__ __forceinline__ float bf2f(unsigned short h) {
  return __uint_as_float(((unsigned int)h) << 16);
}

// ---------------------------------------------------------------------------
// Weight prep:
//  wff[o][(ky*5+kx)*64+ci] bf16  (conv A operand rows)
//  wrec_sw: per-lane MFMA fragment order: for ic-chunk cc (32 chunks of 8),
//  oc row o: wrec_sw[((cc*256)+o)*8 + j] = W_rec[o][cc*8+j]
__global__ void cast_weights(const float* __restrict__ wff_f,
                             const float* __restrict__ wrec_f,
                             unsigned short* __restrict__ wff,
                             unsigned short* __restrict__ wrec_sw) {
  int tid = blockIdx.x * 256 + threadIdx.x;
  if (tid < 409600) {
    int o = tid / 1600, k = tid % 1600;
    int kk = k >> 6, ci = k & 63;            // k = kk*64 + ci
    wff[tid] = f2bf(wff_f[o * 1600 + ci * 25 + kk]);
  } else if (tid < 409600 + 65536) {
    int i = tid - 409600;
    int o = i >> 8, ic = i & 255;
    wrec_sw[(((ic >> 3) << 8) + o) * 8 + (ic & 7)] = f2bf(wrec_f[i]);
  }
}

// ---------------------------------------------------------------------------
// x NCHW fp32 -> NHWC bf16: xt[(b*4096 + y*64 + x)*64 + ci].
__global__ __launch_bounds__(256) void transpose_x(
    const float* __restrict__ x, unsigned short* __restrict__ xt) {
  int g = blockIdx.x * 256 + threadIdx.x;          // 131072 = 32*4096
  const float* src = x + (long)(g >> 12) * CHW + (g & 4095);
  unsigned short* dst = xt + (long)g * 64;
#pragma unroll
  for (int oct = 0; oct < 8; ++oct) {
    alignas(16) unsigned short tmp[8];
#pragma unroll
    for (int d = 0; d < 8; ++d)
      tmp[d] = f2bf(src[(oct * 8 + d) * HW2]);
    *(int4*)(dst + oct * 8) = *(const int4*)tmp;
  }
}

// ---------------------------------------------------------------------------
// Conv as implicit GEMM, D[oc][n] (A = wff, B = x). Block 128oc x 128n,
// BK=32, grid (900, 2). Writes u0 bf16 [n][oc] as uint2 (4 oc per lane).
__global__ __launch_bounds__(256) void conv_kernel(
    const unsigned short* __restrict__ xt,
    const unsigned short* __restrict__ wff,
    unsigned short* __restrict__ u0_nc) {
  __shared__ short As[128 * 40];   // x-tile  [n][k]  pad 32->40
  __shared__ short Bs[128 * 40];   // wff     [oc][k]
  const int t = threadIdx.x;
  const int n0 = blockIdx.x * 128;
  const int oc0 = blockIdx.y * 128;
  const int lane = t & 63, w = t >> 6;
  const int q = lane >> 4, r = lane & 15;
  const int woc = w >> 1, wn = w & 1;      // oc-half, n-half
  const int qt = t & 3, mrow = t >> 2;     // staging: row mrow(+64), 16B qt

  int xbase[2];
#pragma unroll
  for (int p = 0; p < 2; ++p) {
    int n = n0 + p * 64 + mrow;
    int bb = n / 3600, rem = n - bb * 3600;
    int yy = rem / 60, xx = rem - yy * 60;
    xbase[p] = (bb * 4096 + yy * 64 + xx) * 64 + qt * 8;
  }

  f32x4 acc[4][4];
#pragma unroll
  for (int i = 0; i < 4; i++)
#pragma unroll
    for (int j = 0; j < 4; j++) acc[i][j] = (f32x4){0.f, 0.f, 0.f, 0.f};

  for (int c = 0; c < 50; ++c) {
    const int k0 = c * 32;
    const int kk = c >> 1;                 // ky*5+kx, uniform per chunk
    const int ky = kk / 5, kx = kk - ky * 5;
    const int choff = (ky * 64 + kx) * 64 + (c & 1) * 32;  // scalar-uniform

    __syncthreads();
#pragma unroll
    for (int p = 0; p < 2; ++p) {          // wff: 128 oc-rows x 32 k
      int m = p * 64 + mrow;
      *(int4*)(&Bs[m * 40 + qt * 8]) =
          *(const int4*)(wff + (oc0 + m) * 1600 + k0 + qt * 8);
    }
#pragma unroll
    for (int p = 0; p < 2; ++p) {          // x-tile: contiguous bf16 (NHWC)
      int m = p * 64 + mrow;
      *(int4*)(&As[m * 40 + qt * 8]) = *(const int4*)(xt + xbase[p] + choff);
    }
    __syncthreads();

    short8 xf[4], wf[4];
#pragma unroll
    for (int j = 0; j < 4; j++)
      xf[j] = *(const short8*)(&As[(wn * 64 + j * 16 + r) * 40 + q * 8]);
#pragma unroll
    for (int i = 0; i < 4; i++)
      wf[i] = *(const short8*)(&Bs[(woc * 64 + i * 16 + r) * 40 + q * 8]);
#pragma unroll
    for (int i = 0; i < 4; i++)
#pragma unroll
      for (int j = 0; j < 4; j++)
        acc[i][j] = __builtin_amdgcn_mfma_f32_16x16x32_bf16(wf[i], xf[j],
                                                            acc[i][j], 0, 0, 0);
  }

  // epilogue: lane holds 4 consecutive oc (d) at fixed n -> uint2 stores
#pragma unroll
  for (int j = 0; j < 4; j++) {
    const int n = n0 + wn * 64 + j * 16 + r;
#pragma unroll
    for (int i = 0; i < 4; i++) {
      const int oc = oc0 + woc * 64 + i * 16 + q * 4;
      alignas(8) unsigned short up[4];
#pragma unroll
      for (int d = 0; d < 4; ++d) up[d] = f2bf(acc[i][j][d]);
      *(uint2*)(&u0_nc[n * 256 + oc]) = *(const uint2*)up;
    }
  }
}

// ---------------------------------------------------------------------------
// Fused fixed-point iteration. Block = 64 n x 256 oc, grid 1800.
// Stage u-tile -> a in LDS; GEMM A = wrec_sw fragments straight from L2;
// epilogue updates u (bf16 [n][oc]) + norms. One barrier per iteration.
template <int FIRST>
__global__ __launch_bounds__(256, 2) void iter_kernel(
    const unsigned short* __restrict__ wrec_sw,
    const unsigned short* __restrict__ u0, const float* __restrict__ thr,
    unsigned short* __restrict__ u, float* __restrict__ norms,
    int* __restrict__ flag, int it) {
  __shared__ short a_lds[64 * LDA];
  __shared__ float red[8];

  const int t = threadIdx.x;
  if (!FIRST) {
    if (*(volatile int*)flag) return;                      // converged earlier
    float d2p = norms[2 * (it - 1)], n2p = norms[2 * (it - 1) + 1];
    if (d2p < 1e-6f * n2p) {                               // fro ratio < 1e-3
      if (t == 0) *flag = 1;
      return;
    }
  }

  const int n0 = blockIdx.x * 64;
  const unsigned short* src = FIRST ? u0 : u;   // a_t = relu(src_t - thr)

  // ---- stage: read u (or u0) rows, compute a, write LDS ----
#pragma unroll
  for (int p = 0; p < 8; ++p) {
    int s = p * 256 + t;
    int row = s >> 5, ch = s & 31;               // 16B chunk ch of row
    int4 raw = *(const int4*)(src + (n0 + row) * 256 + ch * 8);  // 8 shorts
    const unsigned short* rs = (const unsigned short*)&raw;
    float4 t0 = *(const float4*)(thr + ch * 8);
    float4 t1 = *(const float4*)(thr + ch * 8 + 4);
    const float* tf0 = (const float*)&t0;
    const float* tf1 = (const float*)&t1;
    alignas(16) unsigned short ap[8];
#pragma unroll
    for (int d = 0; d < 8; ++d) {
      float th = (d < 4) ? tf0[d] : tf1[d - 4];
      float v = bf2f(rs[d]) - th;
      ap[d] = f2bf(v > 0.f ? v : 0.f);
    }
    *(int4*)(&a_lds[row * LDA + ch * 8]) = *(const int4*)ap;
  }
  __syncthreads();

  // ---- GEMM: M=256 oc (wave w owns 64), N=64 n, K=256 ----
  const int lane = t & 63, w = t >> 6;
  const int q = lane >> 4, r = lane & 15;

  f32x4 acc[4][4];
#pragma unroll
  for (int i = 0; i < 4; i++)
#pragma unroll
    for (int j = 0; j < 4; j++) acc[i][j] = (f32x4){0.f, 0.f, 0.f, 0.f};

#pragma unroll
  for (int c = 0; c < 8; ++c) {
    short8 afr[4], bfr[4];
#pragma unroll
    for (int i = 0; i < 4; i++)
      afr[i] = *(const short8*)(wrec_sw +
               (((c * 4 + q) << 8) + w * 64 + i * 16 + r) * 8);
#pragma unroll
    for (int j = 0; j < 4; j++)
      bfr[j] = *(const short8*)(&a_lds[(j * 16 + r) * LDA + c * 32 + q * 8]);
#pragma unroll
    for (int i = 0; i < 4; i++)
#pragma unroll
      for (int j = 0; j < 4; j++)
        acc[i][j] = __builtin_amdgcn_mfma_f32_16x16x32_bf16(afr[i], bfr[j],
                                                            acc[i][j], 0, 0, 0);
  }

  // ---- epilogue: u_new = 0.5 u_old + 0.5 (u0 - rec); norms ----
  float d2 = 0.f, n2 = 0.f;
#pragma unroll
  for (int j = 0; j < 4; j++) {
    const int n = n0 + j * 16 + r;
#pragma unroll
    for (int i = 0; i < 4; i++) {
      const int oc = w * 64 + i * 16 + q * 4;
      const int idx = n * 256 + oc;
      uint2 u0p = *(const uint2*)(u0 + idx);
      const unsigned short* u0s = (const unsigned short*)&u0p;
      float uo[4] = {0.f, 0.f, 0.f, 0.f};
      if (!FIRST) {
        uint2 uop = *(const uint2*)(u + idx);
        const unsigned short* us = (const unsigned short*)&uop;
#pragma unroll
        for (int d = 0; d < 4; ++d) uo[d] = bf2f(us[d]);
      }
      alignas(8) unsigned short up[4];
#pragma unroll
      for (int d = 0; d < 4; ++d) {
        float un = 0.5f * uo[d] + 0.5f * (bf2f(u0s[d]) - acc[i][j][d]);
        float df = un - uo[d];
        d2 += df * df;
        n2 += un * un;
        up[d] = f2bf(un);
      }
      *(uint2*)(u + idx) = *(const uint2*)up;
    }
  }

#pragma unroll
  for (int off = 32; off; off >>= 1) {
    d2 += __shfl_down(d2, off, 64);
    n2 += __shfl_down(n2, off, 64);
  }
  if (lane == 0) { red[w] = d2; red[4 + w] = n2; }
  __syncthreads();
  if (t == 0) {
    atomicAdd(&norms[2 * it], red[0] + red[1] + red[2] + red[3]);
    atomicAdd(&norms[2 * it + 1], red[4] + red[5] + red[6] + red[7]);
  }
}

// ---------------------------------------------------------------------------
// Final: out(NCHW fp32) = relu(u - thr), u bf16 [n][oc]. Block = 64 n; wave
// w handles oc [64w, 64w+64).
__global__ __launch_bounds__(256) void final_out(
    const unsigned short* __restrict__ u, const float* __restrict__ thr,
    float* __restrict__ out) {
  const int t = threadIdx.x, lane = t & 63, w = t >> 6;
  const int n = blockIdx.x * 64 + lane;
  const int b = n / 3600, s = n - b * 3600;
  float* ob = out + (long)b * 921600 + s;
  const unsigned short* ub = u + n * 256 + w * 64;
#pragma unroll
  for (int g = 0; g < 16; ++g) {
    uint2 raw = *(const uint2*)(ub + g * 4);
    const unsigned short* rs = (const unsigned short*)&raw;
#pragma unroll
    for (int d = 0; d < 4; ++d) {
      int oc = w * 64 + g * 4 + d;
      float v = bf2f(rs[d]) - thr[oc];
      ob[oc * 3600] = v > 0.f ? v : 0.f;
    }
  }
}

// ---------------------------------------------------------------------------
extern "C" void kernel_launch(void* const* d_in, const int* in_sizes, int n_in,
                              void* d_out, int out_size, void* d_ws,
                              size_t ws_size, hipStream_t stream) {
  const float* x      = (const float*)d_in[0];
  const float* wff_f  = (const float*)d_in[1];
  const float* wrec_f = (const float*)d_in[2];
  const float* thr    = (const float*)d_in[3];
  float* out = (float*)d_out;

  char* ws = (char*)d_ws;
  int* flag = (int*)ws;                                     // [0,4)
  float* norms = (float*)(ws + 64);                         // [64, 400)
  unsigned short* wff     = (unsigned short*)(ws + 1024);     // 819200 B
  unsigned short* wrec_sw = (unsigned short*)(ws + 851968);   // 131072 B
  unsigned short* xt      = (unsigned short*)(ws + 983040);   // 16777216 B
  unsigned short* u0      = (unsigned short*)(ws + 17760256); // 58982400 B
  unsigned short* u       = (unsigned short*)(ws + 76742656); // 58982400 B
  // total ws: ~130 MB

  hipMemsetAsync(d_ws, 0, 1024, stream);  // flag + norm slots
  cast_weights<<<1856, 256, 0, stream>>>(wff_f, wrec_f, wff, wrec_sw);
  transpose_x<<<512, 256, 0, stream>>>(x, xt);
  conv_kernel<<<dim3(900, 2), 256, 0, stream>>>(xt, wff, u0);
  iter_kernel<1><<<1800, 256, 0, stream>>>(wrec_sw, u0, thr, u, norms, flag, 1);
  for (int it = 2; it <= 41; ++it)   // max_iter = 40 -> up to 41 bodies
    iter_kernel<0><<<1800, 256, 0, stream>>>(wrec_sw, u0, thr, u, norms, flag,
                                             it);
  final_out<<<1800, 256, 0, stream>>>(u, thr, out);
}

// Round 6
// 1804.380 us; speedup vs baseline: 2.0036x; 2.0036x over previous
//
#include <hip/hip_runtime.h>

// ---------------------------------------------------------------------------
// SparsePoolingLayer: u0 = conv5x5_valid(x, W_ff); iterate
//   u <- 0.5*u + 0.5*(u0 - W_rec @ a); a = relu(u - thr)
// until ||u_new - u||/||u_new|| < 1e-3 (device-checked), max 41 iterations.
//
// R6: u is fp32 [n][oc] (bf16 u floored the convergence ratio at ~1.1e-3 --
// the bf16 rounding RMS -- so the 1e-3 check never fired and all 41
// iterations ran in R5). Iteration is one fused kernel per step:
//   stage: read u (float4, coalesced), keep in regs, a=relu(u-thr) -> LDS
//   GEMM:  rec = W_rec @ a, wrec pre-swizzled fragments straight from L2
//   rec -> LDS (C-layout -> row-major transpose), barrier
//   update: coalesced u0 int4 + reg u_old -> u_new float4; norms
// HBM/iter ~295 MB -> 47 us floor. xt (conv input, dead after conv) aliases
// the u buffer to keep ws ~170 MB.
// ---------------------------------------------------------------------------

typedef __attribute__((ext_vector_type(8))) short short8;
typedef __attribute__((ext_vector_type(4))) float f32x4;

#define NTOT 115200   // 32*60*60
#define CHW  262144   // 64*64*64
#define HW2  4096     // 64*64
#define LDA  264      // a_lds row stride in shorts (528 B)

__device__ __forceinline__ unsigned short f2bf(float f) {
  unsigned int u = __float_as_uint(f);
  unsigned int r = u + 0x7FFFu + ((u >> 16) & 1u);
  return (unsigned short)(r >> 16);
}
__device__ __forceinline__ float bf2f(unsigned short h) {
  return __uint_as_float(((unsigned int)h) << 16);
}

// ---------------------------------------------------------------------------
// Weight prep:
//  wff[o][(ky*5+kx)*64+ci] bf16  (conv A operand rows)
//  wrec_sw: per-lane MFMA fragment order: for 8-wide ic-chunk cc (0..31),
//  oc row o: wrec_sw[((cc*256)+o)*8 + j] = W_rec[o][cc*8+j]
__global__ void cast_weights(const float* __restrict__ wff_f,
                             const float* __restrict__ wrec_f,
                             unsigned short* __restrict__ wff,
                             unsigned short* __restrict__ wrec_sw) {
  int tid = blockIdx.x * 256 + threadIdx.x;
  if (tid < 409600) {
    int o = tid / 1600, k = tid % 1600;
    int kk = k >> 6, ci = k & 63;            // k = kk*64 + ci
    wff[tid] = f2bf(wff_f[o * 1600 + ci * 25 + kk]);
  } else if (tid < 409600 + 65536) {
    int i = tid - 409600;
    int o = i >> 8, ic = i & 255;
    wrec_sw[(((ic >> 3) << 8) + o) * 8 + (ic & 7)] = f2bf(wrec_f[i]);
  }
}

// ---------------------------------------------------------------------------
// x NCHW fp32 -> NHWC bf16: xt[(b*4096 + y*64 + x)*64 + ci].
__global__ __launch_bounds__(256) void transpose_x(
    const float* __restrict__ x, unsigned short* __restrict__ xt) {
  int g = blockIdx.x * 256 + threadIdx.x;          // 131072 = 32*4096
  const float* src = x + (long)(g >> 12) * CHW + (g & 4095);
  unsigned short* dst = xt + (long)g * 64;
#pragma unroll
  for (int oct = 0; oct < 8; ++oct) {
    alignas(16) unsigned short tmp[8];
#pragma unroll
    for (int d = 0; d < 8; ++d)
      tmp[d] = f2bf(src[(oct * 8 + d) * HW2]);
    *(int4*)(dst + oct * 8) = *(const int4*)tmp;
  }
}

// ---------------------------------------------------------------------------
// Conv as implicit GEMM, D[oc][n] (A = wff, B = x). Block 128oc x 128n,
// BK=32, grid (900, 2). Writes u0 bf16 [n][oc] as uint2 (4 oc per lane).
__global__ __launch_bounds__(256) void conv_kernel(
    const unsigned short* __restrict__ xt,
    const unsigned short* __restrict__ wff,
    unsigned short* __restrict__ u0_nc) {
  __shared__ short As[128 * 40];   // x-tile  [n][k]  pad 32->40
  __shared__ short Bs[128 * 40];   // wff     [oc][k]
  const int t = threadIdx.x;
  const int n0 = blockIdx.x * 128;
  const int oc0 = blockIdx.y * 128;
  const int lane = t & 63, w = t >> 6;
  const int q = lane >> 4, r = lane & 15;
  const int woc = w >> 1, wn = w & 1;      // oc-half, n-half
  const int qt = t & 3, mrow = t >> 2;     // staging: row mrow(+64), 16B qt

  int xbase[2];
#pragma unroll
  for (int p = 0; p < 2; ++p) {
    int n = n0 + p * 64 + mrow;
    int bb = n / 3600, rem = n - bb * 3600;
    int yy = rem / 60, xx = rem - yy * 60;
    xbase[p] = (bb * 4096 + yy * 64 + xx) * 64 + qt * 8;
  }

  f32x4 acc[4][4];
#pragma unroll
  for (int i = 0; i < 4; i++)
#pragma unroll
    for (int j = 0; j < 4; j++) acc[i][j] = (f32x4){0.f, 0.f, 0.f, 0.f};

  for (int c = 0; c < 50; ++c) {
    const int k0 = c * 32;
    const int kk = c >> 1;                 // ky*5+kx, uniform per chunk
    const int ky = kk / 5, kx = kk - ky * 5;
    const int choff = (ky * 64 + kx) * 64 + (c & 1) * 32;  // scalar-uniform

    __syncthreads();
#pragma unroll
    for (int p = 0; p < 2; ++p) {          // wff: 128 oc-rows x 32 k
      int m = p * 64 + mrow;
      *(int4*)(&Bs[m * 40 + qt * 8]) =
          *(const int4*)(wff + (oc0 + m) * 1600 + k0 + qt * 8);
    }
#pragma unroll
    for (int p = 0; p < 2; ++p) {          // x-tile: contiguous bf16 (NHWC)
      int m = p * 64 + mrow;
      *(int4*)(&As[m * 40 + qt * 8]) = *(const int4*)(xt + xbase[p] + choff);
    }
    __syncthreads();

    short8 xf[4], wf[4];
#pragma unroll
    for (int j = 0; j < 4; j++)
      xf[j] = *(const short8*)(&As[(wn * 64 + j * 16 + r) * 40 + q * 8]);
#pragma unroll
    for (int i = 0; i < 4; i++)
      wf[i] = *(const short8*)(&Bs[(woc * 64 + i * 16 + r) * 40 + q * 8]);
#pragma unroll
    for (int i = 0; i < 4; i++)
#pragma unroll
      for (int j = 0; j < 4; j++)
        acc[i][j] = __builtin_amdgcn_mfma_f32_16x16x32_bf16(wf[i], xf[j],
                                                            acc[i][j], 0, 0, 0);
  }

  // epilogue: lane holds 4 consecutive oc (d) at fixed n -> uint2 stores
#pragma unroll
  for (int j = 0; j < 4; j++) {
    const int n = n0 + wn * 64 + j * 16 + r;
#pragma unroll
    for (int i = 0; i < 4; i++) {
      const int oc = oc0 + woc * 64 + i * 16 + q * 4;
      alignas(8) unsigned short up[4];
#pragma unroll
      for (int d = 0; d < 4; ++d) up[d] = f2bf(acc[i][j][d]);
      *(uint2*)(&u0_nc[n * 256 + oc]) = *(const uint2*)up;
    }
  }
}

// ---------------------------------------------------------------------------
// Fused fixed-point iteration. Block = 64 n x 256 oc, grid 1800.
// Phase 1 (stage):  thread (row = p*8 + t>>5, ch = t&31) reads u fp32
//   (2x float4, coalesced), keeps values in regs, writes a bf16 to LDS.
// Phase 2 (GEMM):   M=256 oc (wave w owns 64), N=64 n, K=256; A-fragments
//   from wrec_sw (L2-resident), B from a_lds.
// Phase 3 (rec->LDS): acc (C-layout) stored bf16 into a_lds row-major.
// Phase 4 (update): same mapping as phase 1; u0 int4 + reg u_old ->
//   u_new float4 (coalesced); norm partials -> atomicAdd.
template <int FIRST>
__global__ __launch_bounds__(256, 2) void iter_kernel(
    const unsigned short* __restrict__ wrec_sw,
    const unsigned short* __restrict__ u0, const float* __restrict__ thr,
    float* __restrict__ u, float* __restrict__ norms,
    int* __restrict__ flag, int it) {
  __shared__ short a_lds[64 * LDA];
  __shared__ float red[8];

  const int t = threadIdx.x;
  if (!FIRST) {
    if (*(volatile int*)flag) return;                      // converged earlier
    float d2p = norms[2 * (it - 1)], n2p = norms[2 * (it - 1) + 1];
    if (d2p < 1e-6f * n2p) {                               // fro ratio < 1e-3
      if (t == 0) *flag = 1;
      return;
    }
  }

  const int n0 = blockIdx.x * 64;
  const int ch = t & 31;                   // 8-oc chunk, constant over passes
  const int row0 = t >> 5;                 // rows row0 + 8p
  const int occh = ch * 8;

  // thresholds for my chunk (hoisted: ch is pass-invariant)
  float4 th0 = *(const float4*)(thr + occh);
  float4 th1 = *(const float4*)(thr + occh + 4);
  float thc[8] = {th0.x, th0.y, th0.z, th0.w, th1.x, th1.y, th1.z, th1.w};

  // ---- phase 1: stage u (or u0 on FIRST), keep staged values in regs ----
  float sv[8][8];
#pragma unroll
  for (int p = 0; p < 8; ++p) {
    const int base = (n0 + row0 + p * 8) * 256 + occh;
    if (FIRST) {
      int4 raw = *(const int4*)(u0 + base);      // 8 bf16
      const unsigned short* rs = (const unsigned short*)&raw;
#pragma unroll
      for (int d = 0; d < 8; ++d) sv[p][d] = bf2f(rs[d]);
    } else {
      float4 v0 = *(const float4*)(u + base);
      float4 v1 = *(const float4*)(u + base + 4);
      sv[p][0] = v0.x; sv[p][1] = v0.y; sv[p][2] = v0.z; sv[p][3] = v0.w;
      sv[p][4] = v1.x; sv[p][5] = v1.y; sv[p][6] = v1.z; sv[p][7] = v1.w;
    }
    alignas(16) unsigned short ap[8];
#pragma unroll
    for (int d = 0; d < 8; ++d) {
      float v = sv[p][d] - thc[d];
      ap[d] = f2bf(v > 0.f ? v : 0.f);
    }
    *(int4*)(&a_lds[(row0 + p * 8) * LDA + occh]) = *(const int4*)ap;
  }
  __syncthreads();

  // ---- phase 2: GEMM ----
  const int lane = t & 63, w = t >> 6;
  const int q = lane >> 4, r = lane & 15;

  f32x4 acc[4][4];
#pragma unroll
  for (int i = 0; i < 4; i++)
#pragma unroll
    for (int j = 0; j < 4; j++) acc[i][j] = (f32x4){0.f, 0.f, 0.f, 0.f};

#pragma unroll
  for (int c = 0; c < 8; ++c) {
    short8 afr[4], bfr[4];
#pragma unroll
    for (int i = 0; i < 4; i++)
      afr[i] = *(const short8*)(wrec_sw +
               (((c * 4 + q) << 8) + w * 64 + i * 16 + r) * 8);
#pragma unroll
    for (int j = 0; j < 4; j++)
      bfr[j] = *(const short8*)(&a_lds[(j * 16 + r) * LDA + c * 32 + q * 8]);
#pragma unroll
    for (int i = 0; i < 4; i++)
#pragma unroll
      for (int j = 0; j < 4; j++)
        acc[i][j] = __builtin_amdgcn_mfma_f32_16x16x32_bf16(afr[i], bfr[j],
                                                            acc[i][j], 0, 0, 0);
  }

  // ---- phase 3: rec (C-layout) -> a_lds row-major, bf16 ----
  __syncthreads();                         // all a_lds GEMM reads done
#pragma unroll
  for (int j = 0; j < 4; j++) {
    const int nr = j * 16 + r;
#pragma unroll
    for (int i = 0; i < 4; i++) {
      const int oc = w * 64 + i * 16 + q * 4;
      alignas(8) unsigned short rp[4];
#pragma unroll
      for (int d = 0; d < 4; ++d) rp[d] = f2bf(acc[i][j][d]);
      *(uint2*)(&a_lds[nr * LDA + oc]) = *(const uint2*)rp;
    }
  }
  __syncthreads();

  // ---- phase 4: coalesced u update + norms ----
  float d2 = 0.f, n2 = 0.f;
#pragma unroll
  for (int p = 0; p < 8; ++p) {
    const int base = (n0 + row0 + p * 8) * 256 + occh;
    int4 rr = *(const int4*)(&a_lds[(row0 + p * 8) * LDA + occh]);  // rec
    const unsigned short* rs = (const unsigned short*)&rr;
    float u0v[8];
    if (FIRST) {
#pragma unroll
      for (int d = 0; d < 8; ++d) u0v[d] = sv[p][d];
    } else {
      int4 u0p = *(const int4*)(u0 + base);
      const unsigned short* us = (const unsigned short*)&u0p;
#pragma unroll
      for (int d = 0; d < 8; ++d) u0v[d] = bf2f(us[d]);
    }
    float un[8];
#pragma unroll
    for (int d = 0; d < 8; ++d) {
      float uo = FIRST ? 0.f : sv[p][d];
      un[d] = 0.5f * uo + 0.5f * (u0v[d] - bf2f(rs[d]));
      float df = un[d] - uo;
      d2 += df * df;
      n2 += un[d] * un[d];
    }
    *(float4*)(u + base)     = (float4){un[0], un[1], un[2], un[3]};
    *(float4*)(u + base + 4) = (float4){un[4], un[5], un[6], un[7]};
  }

#pragma unroll
  for (int off = 32; off; off >>= 1) {
    d2 += __shfl_down(d2, off, 64);
    n2 += __shfl_down(n2, off, 64);
  }
  if (lane == 0) { red[w] = d2; red[4 + w] = n2; }
  __syncthreads();
  if (t == 0) {
    atomicAdd(&norms[2 * it], red[0] + red[1] + red[2] + red[3]);
    atomicAdd(&norms[2 * it + 1], red[4] + red[5] + red[6] + red[7]);
  }
}

// ---------------------------------------------------------------------------
// Final: out(NCHW fp32) = relu(u - thr), u fp32 [n][oc]. Block = 64 n; wave
// w handles oc [64w, 64w+64). Reads L1-amortized; writes coalesced in n.
__global__ __launch_bounds__(256) void final_out(
    const float* __restrict__ u, const float* __restrict__ thr,
    float* __restrict__ out) {
  const int t = threadIdx.x, lane = t & 63, w = t >> 6;
  const int n = blockIdx.x * 64 + lane;
  const int b = n / 3600, s = n - b * 3600;
  float* ob = out + (long)b * 921600 + s;
  const float* ub = u + (long)n * 256 + w * 64;
#pragma unroll
  for (int g = 0; g < 16; ++g) {
    float4 v = *(const float4*)(ub + g * 4);
    const float* vf = (const float*)&v;
#pragma unroll
    for (int d = 0; d < 4; ++d) {
      int oc = w * 64 + g * 4 + d;
      float r = vf[d] - thr[oc];
      ob[oc * 3600] = r > 0.f ? r : 0.f;
    }
  }
}

// ---------------------------------------------------------------------------
extern "C" void kernel_launch(void* const* d_in, const int* in_sizes, int n_in,
                              void* d_out, int out_size, void* d_ws,
                              size_t ws_size, hipStream_t stream) {
  const float* x      = (const float*)d_in[0];
  const float* wff_f  = (const float*)d_in[1];
  const float* wrec_f = (const float*)d_in[2];
  const float* thr    = (const float*)d_in[3];
  float* out = (float*)d_out;

  char* ws = (char*)d_ws;
  int* flag = (int*)ws;                                      // [0,4)
  float* norms = (float*)(ws + 64);                          // [64, 400)
  unsigned short* wff     = (unsigned short*)(ws + 1024);      // 819200 B
  unsigned short* wrec_sw = (unsigned short*)(ws + 851968);    // 131072 B
  // xt (16.8 MB) aliases the head of u (117.96 MB): xt is consumed by
  // conv_kernel, u is first written by iter_kernel<1> afterwards.
  unsigned short* xt = (unsigned short*)(ws + 983040);
  float*          u  = (float*)(ws + 983040);                 // 117964800 B
  unsigned short* u0 = (unsigned short*)(ws + 983040 + 117964800); // 58.98 MB
  // total ws: ~169.7 MB

  hipMemsetAsync(d_ws, 0, 1024, stream);  // flag + norm slots
  cast_weights<<<1856, 256, 0, stream>>>(wff_f, wrec_f, wff, wrec_sw);
  transpose_x<<<512, 256, 0, stream>>>(x, xt);
  conv_kernel<<<dim3(900, 2), 256, 0, stream>>>(xt, wff, u0);
  iter_kernel<1><<<1800, 256, 0, stream>>>(wrec_sw, u0, thr, u, norms, flag, 1);
  for (int it = 2; it <= 41; ++it)   // max_iter = 40 -> up to 41 bodies
    iter_kernel<0><<<1800, 256, 0, stream>>>(wrec_sw, u0, thr, u, norms, flag,
                                             it);
  final_out<<<1800, 256, 0, stream>>>(u, thr, out);
}

// Round 8
// 1538.528 us; speedup vs baseline: 2.3498x; 1.1728x over previous
//
#include <hip/hip_runtime.h>

// ---------------------------------------------------------------------------
// SparsePoolingLayer: u0 = conv5x5_valid(x, W_ff); iterate
//   u <- 0.5*u + 0.5*(u0 - W_rec @ a); a = relu(u - thr)
// until ||u_new - u||/||u_new|| < 1e-3 (device-checked), max 41 iterations.
//
// R7 design (R8 = bugfix): u stored fp16 [n][oc]. fp16 keeps the
// convergence-check noise floor at ~1.4e-4 (11-bit mantissa) -- below the
// 1e-3 threshold that bf16 (~1.1e-3) violated in R5 -- and cuts iteration
// traffic to 177 MB (fp32 was 295 MB, measured ~95us/iter). Staged u kept
// packed fp16 in 32 VGPRs; rec round-trips LDS as fp16; launch_bounds
// (256,3). R8 fix: final_out loop bound was g<16 with 8-oc int4 groups ->
// each wave covered 128 oc; w=3 wrote oc 256..319 = batch b+1 channels
// 0..63 with garbage-threshold values (absmax 5.06). Now g<8.
// ---------------------------------------------------------------------------

typedef __attribute__((ext_vector_type(8))) short short8;
typedef __attribute__((ext_vector_type(4))) float f32x4;

#define NTOT 115200   // 32*60*60
#define CHW  262144   // 64*64*64
#define HW2  4096     // 64*64
#define LDA  264      // a_lds row stride in shorts (528 B)

__device__ __forceinline__ unsigned short f2bf(float f) {
  unsigned int u = __float_as_uint(f);
  unsigned int r = u + 0x7FFFu + ((u >> 16) & 1u);
  return (unsigned short)(r >> 16);
}
__device__ __forceinline__ float bf2f(unsigned short h) {
  return __uint_as_float(((unsigned int)h) << 16);
}
__device__ __forceinline__ unsigned short f2h(float f) {
  _Float16 x = (_Float16)f;
  unsigned short r;
  __builtin_memcpy(&r, &x, 2);
  return r;
}
__device__ __forceinline__ float h2f(unsigned short h) {
  _Float16 x;
  __builtin_memcpy(&x, &h, 2);
  return (float)x;
}

// ---------------------------------------------------------------------------
// Weight prep:
//  wff[o][(ky*5+kx)*64+ci] bf16  (conv A operand rows)
//  wrec_sw: per-lane MFMA fragment order: for 8-wide ic-chunk cc (0..31),
//  oc row o: wrec_sw[((cc*256)+o)*8 + j] = W_rec[o][cc*8+j]
__global__ void cast_weights(const float* __restrict__ wff_f,
                             const float* __restrict__ wrec_f,
                             unsigned short* __restrict__ wff,
                             unsigned short* __restrict__ wrec_sw) {
  int tid = blockIdx.x * 256 + threadIdx.x;
  if (tid < 409600) {
    int o = tid / 1600, k = tid % 1600;
    int kk = k >> 6, ci = k & 63;            // k = kk*64 + ci
    wff[tid] = f2bf(wff_f[o * 1600 + ci * 25 + kk]);
  } else if (tid < 409600 + 65536) {
    int i = tid - 409600;
    int o = i >> 8, ic = i & 255;
    wrec_sw[(((ic >> 3) << 8) + o) * 8 + (ic & 7)] = f2bf(wrec_f[i]);
  }
}

// ---------------------------------------------------------------------------
// x NCHW fp32 -> NHWC bf16: xt[(b*4096 + y*64 + x)*64 + ci].
__global__ __launch_bounds__(256) void transpose_x(
    const float* __restrict__ x, unsigned short* __restrict__ xt) {
  int g = blockIdx.x * 256 + threadIdx.x;          // 131072 = 32*4096
  const float* src = x + (long)(g >> 12) * CHW + (g & 4095);
  unsigned short* dst = xt + (long)g * 64;
#pragma unroll
  for (int oct = 0; oct < 8; ++oct) {
    alignas(16) unsigned short tmp[8];
#pragma unroll
    for (int d = 0; d < 8; ++d)
      tmp[d] = f2bf(src[(oct * 8 + d) * HW2]);
    *(int4*)(dst + oct * 8) = *(const int4*)tmp;
  }
}

// ---------------------------------------------------------------------------
// Conv as implicit GEMM, D[oc][n] (A = wff, B = x). Block 128oc x 128n,
// BK=32, grid (900, 2). Writes u0 bf16 [n][oc] as uint2 (4 oc per lane).
__global__ __launch_bounds__(256) void conv_kernel(
    const unsigned short* __restrict__ xt,
    const unsigned short* __restrict__ wff,
    unsigned short* __restrict__ u0_nc) {
  __shared__ short As[128 * 40];   // x-tile  [n][k]  pad 32->40
  __shared__ short Bs[128 * 40];   // wff     [oc][k]
  const int t = threadIdx.x;
  const int n0 = blockIdx.x * 128;
  const int oc0 = blockIdx.y * 128;
  const int lane = t & 63, w = t >> 6;
  const int q = lane >> 4, r = lane & 15;
  const int woc = w >> 1, wn = w & 1;      // oc-half, n-half
  const int qt = t & 3, mrow = t >> 2;     // staging: row mrow(+64), 16B qt

  int xbase[2];
#pragma unroll
  for (int p = 0; p < 2; ++p) {
    int n = n0 + p * 64 + mrow;
    int bb = n / 3600, rem = n - bb * 3600;
    int yy = rem / 60, xx = rem - yy * 60;
    xbase[p] = (bb * 4096 + yy * 64 + xx) * 64 + qt * 8;
  }

  f32x4 acc[4][4];
#pragma unroll
  for (int i = 0; i < 4; i++)
#pragma unroll
    for (int j = 0; j < 4; j++) acc[i][j] = (f32x4){0.f, 0.f, 0.f, 0.f};

  for (int c = 0; c < 50; ++c) {
    const int k0 = c * 32;
    const int kk = c >> 1;                 // ky*5+kx, uniform per chunk
    const int ky = kk / 5, kx = kk - ky * 5;
    const int choff = (ky * 64 + kx) * 64 + (c & 1) * 32;  // scalar-uniform

    __syncthreads();
#pragma unroll
    for (int p = 0; p < 2; ++p) {          // wff: 128 oc-rows x 32 k
      int m = p * 64 + mrow;
      *(int4*)(&Bs[m * 40 + qt * 8]) =
          *(const int4*)(wff + (oc0 + m) * 1600 + k0 + qt * 8);
    }
#pragma unroll
    for (int p = 0; p < 2; ++p) {          // x-tile: contiguous bf16 (NHWC)
      int m = p * 64 + mrow;
      *(int4*)(&As[m * 40 + qt * 8]) = *(const int4*)(xt + xbase[p] + choff);
    }
    __syncthreads();

    short8 xf[4], wf[4];
#pragma unroll
    for (int j = 0; j < 4; j++)
      xf[j] = *(const short8*)(&As[(wn * 64 + j * 16 + r) * 40 + q * 8]);
#pragma unroll
    for (int i = 0; i < 4; i++)
      wf[i] = *(const short8*)(&Bs[(woc * 64 + i * 16 + r) * 40 + q * 8]);
#pragma unroll
    for (int i = 0; i < 4; i++)
#pragma unroll
      for (int j = 0; j < 4; j++)
        acc[i][j] = __builtin_amdgcn_mfma_f32_16x16x32_bf16(wf[i], xf[j],
                                                            acc[i][j], 0, 0, 0);
  }

  // epilogue: lane holds 4 consecutive oc (d) at fixed n -> uint2 stores
#pragma unroll
  for (int j = 0; j < 4; j++) {
    const int n = n0 + wn * 64 + j * 16 + r;
#pragma unroll
    for (int i = 0; i < 4; i++) {
      const int oc = oc0 + woc * 64 + i * 16 + q * 4;
      alignas(8) unsigned short up[4];
#pragma unroll
      for (int d = 0; d < 4; ++d) up[d] = f2bf(acc[i][j][d]);
      *(uint2*)(&u0_nc[n * 256 + oc]) = *(const uint2*)up;
    }
  }
}

// ---------------------------------------------------------------------------
// Fused fixed-point iteration. Block = 64 n x 256 oc, grid 1800.
// P1: thread (row = row0+8p, ch) reads u fp16 int4 (coalesced), keeps the
//     packed halves in regs, writes a bf16 to LDS.
// P2: GEMM M=256 oc (wave w owns 64), N=64 n, K=256; A-frags from wrec_sw
//     (L2-resident), B from a_lds.
// P3: rec (C-layout) -> a_lds as fp16 row-major.
// P4: coalesced u0 int4 + packed reg u_old -> u_new fp16 int4; norms.
template <int FIRST>
__global__ __launch_bounds__(256, 3) void iter_kernel(
    const unsigned short* __restrict__ wrec_sw,
    const unsigned short* __restrict__ u0, const float* __restrict__ thr,
    unsigned short* __restrict__ u, float* __restrict__ norms,
    int* __restrict__ flag, int it) {
  __shared__ short a_lds[64 * LDA];
  __shared__ float red[8];

  const int t = threadIdx.x;
  if (!FIRST) {
    if (*(volatile int*)flag) return;                      // converged earlier
    float d2p = norms[2 * (it - 1)], n2p = norms[2 * (it - 1) + 1];
    if (d2p < 1e-6f * n2p) {                               // fro ratio < 1e-3
      if (t == 0) *flag = 1;
      return;
    }
  }

  const int n0 = blockIdx.x * 64;
  const int ch = t & 31;                   // 8-oc chunk
  const int row0 = t >> 5;                 // rows row0 + 8p
  const int occh = ch * 8;

  float4 th0 = *(const float4*)(thr + occh);
  float4 th1 = *(const float4*)(thr + occh + 4);
  float thc[8] = {th0.x, th0.y, th0.z, th0.w, th1.x, th1.y, th1.z, th1.w};

  // ---- phase 1: stage; sv = packed fp16 of staged value ----
  int4 sv[8];
#pragma unroll
  for (int p = 0; p < 8; ++p) {
    const int base = (n0 + row0 + p * 8) * 256 + occh;
    alignas(16) unsigned short ap[8];
    if (FIRST) {
      int4 raw = *(const int4*)(u0 + base);        // 8 bf16
      const unsigned short* rs = (const unsigned short*)&raw;
      alignas(16) unsigned short hp[8];
#pragma unroll
      for (int d = 0; d < 8; ++d) {
        float v = bf2f(rs[d]);
        hp[d] = f2h(v);                            // exact (bf16 subset fp16)
        float a = v - thc[d];
        ap[d] = f2bf(a > 0.f ? a : 0.f);
      }
      sv[p] = *(const int4*)hp;
    } else {
      sv[p] = *(const int4*)(u + base);            // 8 fp16
      const unsigned short* hs = (const unsigned short*)&sv[p];
#pragma unroll
      for (int d = 0; d < 8; ++d) {
        float a = h2f(hs[d]) - thc[d];
        ap[d] = f2bf(a > 0.f ? a : 0.f);
      }
    }
    *(int4*)(&a_lds[(row0 + p * 8) * LDA + occh]) = *(const int4*)ap;
  }
  __syncthreads();

  // ---- phase 2: GEMM ----
  const int lane = t & 63, w = t >> 6;
  const int q = lane >> 4, r = lane & 15;

  f32x4 acc[4][4];
#pragma unroll
  for (int i = 0; i < 4; i++)
#pragma unroll
    for (int j = 0; j < 4; j++) acc[i][j] = (f32x4){0.f, 0.f, 0.f, 0.f};

#pragma unroll
  for (int c = 0; c < 8; ++c) {
    short8 afr[4], bfr[4];
#pragma unroll
    for (int i = 0; i < 4; i++)
      afr[i] = *(const short8*)(wrec_sw +
               (((c * 4 + q) << 8) + w * 64 + i * 16 + r) * 8);
#pragma unroll
    for (int j = 0; j < 4; j++)
      bfr[j] = *(const short8*)(&a_lds[(j * 16 + r) * LDA + c * 32 + q * 8]);
#pragma unroll
    for (int i = 0; i < 4; i++)
#pragma unroll
      for (int j = 0; j < 4; j++)
        acc[i][j] = __builtin_amdgcn_mfma_f32_16x16x32_bf16(afr[i], bfr[j],
                                                            acc[i][j], 0, 0, 0);
  }

  // ---- phase 3: rec (C-layout) -> a_lds row-major, fp16 ----
  __syncthreads();                         // all a_lds GEMM reads done
#pragma unroll
  for (int j = 0; j < 4; j++) {
    const int nr = j * 16 + r;
#pragma unroll
    for (int i = 0; i < 4; i++) {
      const int oc = w * 64 + i * 16 + q * 4;
      alignas(8) unsigned short rp[4];
#pragma unroll
      for (int d = 0; d < 4; ++d) rp[d] = f2h(acc[i][j][d]);
      *(uint2*)(&a_lds[nr * LDA + oc]) = *(const uint2*)rp;
    }
  }
  __syncthreads();

  // ---- phase 4: coalesced u update + norms ----
  float d2 = 0.f, n2 = 0.f;
#pragma unroll
  for (int p = 0; p < 8; ++p) {
    const int base = (n0 + row0 + p * 8) * 256 + occh;
    int4 rr = *(const int4*)(&a_lds[(row0 + p * 8) * LDA + occh]);  // rec fp16
    const unsigned short* rs = (const unsigned short*)&rr;
    const unsigned short* hs = (const unsigned short*)&sv[p];
    float u0v[8];
    if (FIRST) {
#pragma unroll
      for (int d = 0; d < 8; ++d) u0v[d] = h2f(hs[d]);
    } else {
      int4 u0p = *(const int4*)(u0 + base);
      const unsigned short* us = (const unsigned short*)&u0p;
#pragma unroll
      for (int d = 0; d < 8; ++d) u0v[d] = bf2f(us[d]);
    }
    alignas(16) unsigned short up[8];
#pragma unroll
    for (int d = 0; d < 8; ++d) {
      float uo = FIRST ? 0.f : h2f(hs[d]);
      float un = 0.5f * uo + 0.5f * (u0v[d] - h2f(rs[d]));
      float df = un - uo;
      d2 += df * df;
      n2 += un * un;
      up[d] = f2h(un);
    }
    *(int4*)(u + base) = *(const int4*)up;
  }

#pragma unroll
  for (int off = 32; off; off >>= 1) {
    d2 += __shfl_down(d2, off, 64);
    n2 += __shfl_down(n2, off, 64);
  }
  if (lane == 0) { red[w] = d2; red[4 + w] = n2; }
  __syncthreads();
  if (t == 0) {
    atomicAdd(&norms[2 * it], red[0] + red[1] + red[2] + red[3]);
    atomicAdd(&norms[2 * it + 1], red[4] + red[5] + red[6] + red[7]);
  }
}

// ---------------------------------------------------------------------------
// Final: out(NCHW fp32) = relu(u - thr), u fp16 [n][oc]. Block = 64 n; wave
// w handles oc [64w, 64w+64) = 8 int4 groups of 8 fp16.
__global__ __launch_bounds__(256) void final_out(
    const unsigned short* __restrict__ u, const float* __restrict__ thr,
    float* __restrict__ out) {
  const int t = threadIdx.x, lane = t & 63, w = t >> 6;
  const int n = blockIdx.x * 64 + lane;
  const int b = n / 3600, s = n - b * 3600;
  float* ob = out + (long)b * 921600 + s;
  const unsigned short* ub = u + (long)n * 256 + w * 64;
#pragma unroll
  for (int g = 0; g < 8; ++g) {            // 8 groups x 8 fp16 = 64 oc
    int4 raw = *(const int4*)(ub + g * 8);
    const unsigned short* rs = (const unsigned short*)&raw;
#pragma unroll
    for (int d = 0; d < 8; ++d) {
      int oc = w * 64 + g * 8 + d;
      float v = h2f(rs[d]) - thr[oc];
      ob[oc * 3600] = v > 0.f ? v : 0.f;
    }
  }
}

// ---------------------------------------------------------------------------
extern "C" void kernel_launch(void* const* d_in, const int* in_sizes, int n_in,
                              void* d_out, int out_size, void* d_ws,
                              size_t ws_size, hipStream_t stream) {
  const float* x      = (const float*)d_in[0];
  const float* wff_f  = (const float*)d_in[1];
  const float* wrec_f = (const float*)d_in[2];
  const float* thr    = (const float*)d_in[3];
  float* out = (float*)d_out;

  char* ws = (char*)d_ws;
  int* flag = (int*)ws;                                      // [0,4)
  float* norms = (float*)(ws + 64);                          // [64, 400)
  unsigned short* wff     = (unsigned short*)(ws + 1024);      // 819200 B
  unsigned short* wrec_sw = (unsigned short*)(ws + 851968);    // 131072 B
  // xt (16.8 MB) aliases the head of u (59 MB): xt dies after conv, u is
  // first written by iter_kernel<1>.
  unsigned short* xt = (unsigned short*)(ws + 983040);
  unsigned short* u  = (unsigned short*)(ws + 983040);         // 58982400 B
  unsigned short* u0 = (unsigned short*)(ws + 59965440);       // 58982400 B
  // total ws: ~119 MB

  hipMemsetAsync(d_ws, 0, 1024, stream);  // flag + norm slots
  cast_weights<<<1856, 256, 0, stream>>>(wff_f, wrec_f, wff, wrec_sw);
  transpose_x<<<512, 256, 0, stream>>>(x, xt);
  conv_kernel<<<dim3(900, 2), 256, 0, stream>>>(xt, wff, u0);
  iter_kernel<1><<<1800, 256, 0, stream>>>(wrec_sw, u0, thr, u, norms, flag, 1);
  for (int it = 2; it <= 41; ++it)   // max_iter = 40 -> up to 41 bodies
    iter_kernel<0><<<1800, 256, 0, stream>>>(wrec_sw, u0, thr, u, norms, flag,
                                             it);
  final_out<<<1800, 256, 0, stream>>>(u, thr, out);
}